// Round 5
// baseline (70105.505 us; speedup 1.0000x reference)
//
#include <hip/hip_runtime.h>
#include <math.h>

#define B_ 128
#define T_ 256
#define H_ 512
#define O_ 256
#define X_ 768

// ---- module-scope fp32 scratch ----
__device__ float g_hp[(size_t)B_ * T_ * H_];  // 67 MB h_proj
__device__ float g_s[2][B_ * H_];
__device__ float g_y1[B_ * H_];
__device__ float g_y2[B_ * H_];
__device__ float g_sp[B_ * H_];
__device__ float g_e[B_ * T_];
__device__ float g_a[B_ * T_];
__device__ float g_x[B_ * X_];
__device__ float g_r[B_ * H_];
__device__ float g_u[B_ * H_];

// ---- s0 -> state buffer 0 ----
__global__ void init_kernel(const float* __restrict__ s0) {
  int g = blockIdx.x * blockDim.x + threadIdx.x;
  if (g < B_ * H_) g_s[0][g] = s0[g];
}

// ---- h_proj[m][n] = sum_k h[m][k] * We1[k][n]   (one block per m) ----
__global__ void __launch_bounds__(512) hproj_kernel(const float* __restrict__ h,
                                                    const float* __restrict__ We1) {
  const int m = blockIdx.x;     // 0 .. B*T-1
  const int n = threadIdx.x;    // 0 .. 511
  const float* hr = h + (size_t)m * H_;
  float acc = 0.f;
  for (int k = 0; k < H_; ++k)
    acc += hr[k] * We1[(size_t)k * H_ + n];
  g_hp[(size_t)m * H_ + n] = acc;
}

// ---- kA: y1 = tanh(s@Wy1+by1)  |  sp = s@We1[H:]+be1 ----
__global__ void __launch_bounds__(512) kA(const float* __restrict__ Wy1,
                                          const float* __restrict__ by1,
                                          const float* __restrict__ We1,
                                          const float* __restrict__ be1, int t) {
  const int b = blockIdx.x, n = threadIdx.x;
  const float* s = g_s[t & 1] + b * H_;
  if (blockIdx.y == 0) {
    float acc = by1[n];
    for (int k = 0; k < H_; ++k) acc += s[k] * Wy1[(size_t)k * H_ + n];
    g_y1[b * H_ + n] = tanhf(acc);
  } else {
    float acc = be1[n];
    for (int k = 0; k < H_; ++k) acc += s[k] * We1[(size_t)(H_ + k) * H_ + n];
    g_sp[b * H_ + n] = acc;
  }
}

// ---- kB: y2 = tanh(y1@Wy2+by2) ; e[tp] = sum_k tanh(hp+sp)*We2 + be2 ----
__global__ void __launch_bounds__(512) kB(const float* __restrict__ Wy2,
                                          const float* __restrict__ by2,
                                          const float* __restrict__ We2,
                                          const float* __restrict__ be2) {
  const int b = blockIdx.x, n = threadIdx.x;  // 512 threads
  {
    float acc = by2[n];
    const float* y1 = g_y1 + b * H_;
    for (int k = 0; k < H_; ++k) acc += y1[k] * Wy2[(size_t)k * H_ + n];
    g_y2[b * H_ + n] = tanhf(acc);
  }
  if (n < T_) {
    const int tp = n;
    const float* hp = g_hp + (size_t)(b * T_ + tp) * H_;
    const float* sp = g_sp + b * H_;
    float e = 0.f;
    for (int k = 0; k < H_; ++k) e += tanhf(hp[k] + sp[k]) * We2[k];
    g_e[b * T_ + tp] = e + be2[0];
  }
}

// ---- kC: y = y2@Wy3+by3 -> x[:,0:256] & out (fp32) ; a = softmax(e) ----
__global__ void __launch_bounds__(256) kC(const float* __restrict__ Wy3,
                                          const float* __restrict__ by3,
                                          float* __restrict__ out, int t) {
  __shared__ float sb[256];
  const int b = blockIdx.x, n = threadIdx.x;  // 256 threads
  {
    float acc = by3[n];
    const float* y2 = g_y2 + b * H_;
    for (int k = 0; k < H_; ++k) acc += y2[k] * Wy3[(size_t)k * O_ + n];
    g_x[b * X_ + n] = acc;
    out[((size_t)b * T_ + t) * O_ + n] = acc;   // fp32 store
  }
  const float e = g_e[b * T_ + n];
  sb[n] = e;
  __syncthreads();
  for (int off = 128; off > 0; off >>= 1) {
    if (n < off) sb[n] = fmaxf(sb[n], sb[n + off]);
    __syncthreads();
  }
  const float m = sb[0];
  __syncthreads();
  const float pe = expf(e - m);
  sb[n] = pe;
  __syncthreads();
  for (int off = 128; off > 0; off >>= 1) {
    if (n < off) sb[n] = sb[n] + sb[n + off];
    __syncthreads();
  }
  g_a[b * T_ + n] = pe / sb[0];
}

// ---- kD: c = sum_tp a*h -> x[:,256:768] ----
__global__ void __launch_bounds__(512) kD(const float* __restrict__ h) {
  const int b = blockIdx.x, n = threadIdx.x;  // 512 threads
  const float* hb = h + (size_t)b * T_ * H_ + n;
  const float* a = g_a + b * T_;
  float acc = 0.f;
  for (int tp = 0; tp < T_; ++tp) acc += a[tp] * hb[(size_t)tp * H_];
  g_x[b * X_ + O_ + n] = acc;
}

// ---- kE: r|u = sigmoid(x@Wx + s@Wh + b) ----
__global__ void __launch_bounds__(1024) kE(const float* __restrict__ Wxr,
                                           const float* __restrict__ Whr,
                                           const float* __restrict__ br,
                                           const float* __restrict__ Wxu,
                                           const float* __restrict__ Whu,
                                           const float* __restrict__ bu, int t) {
  const int b = blockIdx.x, c = threadIdx.x;  // 1024 threads
  const bool isU = (c >= H_);
  const int n = isU ? (c - H_) : c;
  const float* Wx = isU ? Wxu : Wxr;
  const float* Wh = isU ? Whu : Whr;
  float acc = (isU ? bu : br)[n];
  const float* x = g_x + b * X_;
  const float* s = g_s[t & 1] + b * H_;
  for (int k = 0; k < X_; ++k) acc += x[k] * Wx[(size_t)k * H_ + n];
  for (int k = 0; k < H_; ++k) acc += s[k] * Wh[(size_t)k * H_ + n];
  const float g = 1.f / (1.f + expf(-acc));
  (isU ? g_u : g_r)[b * H_ + n] = g;
}

// ---- kF: h_cand = tanh(x@Wxh + (r*s)@Whh) ; s' = (1-u)*hc + u*s ----
__global__ void __launch_bounds__(512) kF(const float* __restrict__ Wxh,
                                          const float* __restrict__ Whh, int t) {
  const int b = blockIdx.x, n = threadIdx.x;  // 512 threads
  const float* x = g_x + b * X_;
  const float* s = g_s[t & 1] + b * H_;
  const float* r = g_r + b * H_;
  float acc = 0.f;
  for (int k = 0; k < X_; ++k) acc += x[k] * Wxh[(size_t)k * H_ + n];
  for (int k = 0; k < H_; ++k) acc += (r[k] * s[k]) * Whh[(size_t)k * H_ + n];
  const float hc = tanhf(acc);
  const float u = g_u[b * H_ + n];
  g_s[(t + 1) & 1][b * H_ + n] = (1.f - u) * hc + u * s[n];
}

extern "C" void kernel_launch(void* const* d_in, const int* in_sizes, int n_in,
                              void* d_out, int out_size, void* d_ws, size_t ws_size,
                              hipStream_t stream) {
  (void)in_sizes; (void)n_in; (void)out_size; (void)d_ws; (void)ws_size;
  const float* h   = (const float*)d_in[0];
  const float* s0  = (const float*)d_in[1];
  const float* Wy1 = (const float*)d_in[2];
  const float* by1 = (const float*)d_in[3];
  const float* Wy2 = (const float*)d_in[4];
  const float* by2 = (const float*)d_in[5];
  const float* Wy3 = (const float*)d_in[6];
  const float* by3 = (const float*)d_in[7];
  const float* We1 = (const float*)d_in[8];
  const float* be1 = (const float*)d_in[9];
  const float* We2 = (const float*)d_in[10];
  const float* be2 = (const float*)d_in[11];
  const float* Wxr = (const float*)d_in[12];
  const float* Whr = (const float*)d_in[13];
  const float* br  = (const float*)d_in[14];
  const float* Wxu = (const float*)d_in[15];
  const float* Whu = (const float*)d_in[16];
  const float* bu  = (const float*)d_in[17];
  const float* Wxh = (const float*)d_in[18];
  const float* Whh = (const float*)d_in[19];
  float* out = (float*)d_out;

  hipLaunchKernelGGL(init_kernel, dim3(128), dim3(512), 0, stream, s0);
  hipLaunchKernelGGL(hproj_kernel, dim3(B_ * T_), dim3(512), 0, stream, h, We1);

  for (int t = 0; t < T_; ++t) {
    hipLaunchKernelGGL(kA, dim3(B_, 2), dim3(512), 0, stream, Wy1, by1, We1, be1, t);
    hipLaunchKernelGGL(kB, dim3(B_), dim3(512), 0, stream, Wy2, by2, We2, be2);
    hipLaunchKernelGGL(kC, dim3(B_), dim3(256), 0, stream, Wy3, by3, out, t);
    hipLaunchKernelGGL(kD, dim3(B_), dim3(512), 0, stream, h);
    hipLaunchKernelGGL(kE, dim3(B_), dim3(1024), 0, stream, Wxr, Whr, br, Wxu, Whu, bu, t);
    hipLaunchKernelGGL(kF, dim3(B_), dim3(512), 0, stream, Wxh, Whh, t);
  }
}

// Round 6
// 22069.250 us; speedup vs baseline: 3.1766x; 3.1766x over previous
//
#include <hip/hip_runtime.h>

#define B_ 128
#define T_ 256
#define H_ 512
#define O_ 256
#define X_ 768

typedef unsigned short u16;
typedef unsigned int u32;

#if __has_builtin(__builtin_amdgcn_exp2f)
#define EXP2(x) __builtin_amdgcn_exp2f(x)
#else
#define EXP2(x) exp2f(x)
#endif
#if __has_builtin(__builtin_amdgcn_rcpf)
#define RCPF(x) __builtin_amdgcn_rcpf(x)
#else
#define RCPF(x) (1.0f / (x))
#endif

#define LOG2E_F 1.4426950408889634f
#define TWOLOG2E_F 2.8853900817779268f

__device__ __forceinline__ float bf2f(u16 v) {
  union { u32 u; float f; } c; c.u = ((u32)v) << 16; return c.f;
}
__device__ __forceinline__ u16 f2bf(float f) {
  union { float f; u32 u; } c; c.f = f;
  return (u16)((c.u + 0x7FFFu + ((c.u >> 16) & 1u)) >> 16);
}
__device__ __forceinline__ float ftanh(float x) {
  x = fminf(fmaxf(x, -40.f), 40.f);
  float z = EXP2(x * TWOLOG2E_F);
  return (z - 1.0f) * RCPF(z + 1.0f);
}
__device__ __forceinline__ float fsigm(float x) {
  x = fminf(fmaxf(x, -40.f), 40.f);
  return RCPF(1.0f + EXP2(-x * LOG2E_F));
}

// ---- module-scope scratch ----
__device__ u16 g_hp[(size_t)B_ * T_ * H_];   // bf16 h_proj (33.5 MB)
__device__ u16 g_hb[(size_t)B_ * T_ * H_];   // bf16 copy of h (33.5 MB)
__device__ float g_sA[B_ * H_];
__device__ float g_sB[B_ * H_];
__device__ float g_x[B_ * X_];
__device__ float g_r[B_ * H_];
__device__ float g_u[B_ * H_];

// bf16 weight copies
__device__ u16 cWy1[H_ * H_];
__device__ u16 cby1[H_];
__device__ u16 cWy2[H_ * H_];
__device__ u16 cby2[H_];
__device__ u16 cWy3[H_ * O_];
__device__ u16 cby3[O_];
__device__ u16 cWe1[2 * H_ * H_];
__device__ u16 cbe1[H_];
__device__ u16 cWe2[H_];
__device__ u16 cWxr[X_ * H_];
__device__ u16 cWhr[H_ * H_];
__device__ u16 cbr[H_];
__device__ u16 cWxu[X_ * H_];
__device__ u16 cWhu[H_ * H_];
__device__ u16 cbu[H_];
__device__ u16 cWxh[X_ * H_];
__device__ u16 cWhh[H_ * H_];

#define DEF_CONV(NAME, ARR, N)                                     \
  __global__ void conv_##NAME(const float* __restrict__ s) {       \
    int i = blockIdx.x * 256 + threadIdx.x;                        \
    if (i < (N)) ARR[i] = f2bf(s[i]);                              \
  }

DEF_CONV(Wy1, cWy1, H_ * H_)
DEF_CONV(by1, cby1, H_)
DEF_CONV(Wy2, cWy2, H_ * H_)
DEF_CONV(by2, cby2, H_)
DEF_CONV(Wy3, cWy3, H_ * O_)
DEF_CONV(by3, cby3, O_)
DEF_CONV(We1, cWe1, 2 * H_ * H_)
DEF_CONV(be1, cbe1, H_)
DEF_CONV(We2, cWe2, H_)
DEF_CONV(Wxr, cWxr, X_ * H_)
DEF_CONV(Whr, cWhr, H_ * H_)
DEF_CONV(br, cbr, H_)
DEF_CONV(Wxu, cWxu, X_ * H_)
DEF_CONV(Whu, cWhu, H_ * H_)
DEF_CONV(bu, cbu, H_)
DEF_CONV(Wxh, cWxh, X_ * H_)
DEF_CONV(Whh, cWhh, H_ * H_)

__global__ void conv_h(const float* __restrict__ s) {
  size_t i = (size_t)blockIdx.x * 256 + threadIdx.x;
  g_hb[i] = f2bf(s[i]);
}

__global__ void init_kernel(const float* __restrict__ s0) {
  int g = blockIdx.x * blockDim.x + threadIdx.x;
  if (g < B_ * H_) g_sA[g] = s0[g];
}

// ---- h_proj = h @ We1[:H]  (fp32 in, bf16 out) ----
__global__ void __launch_bounds__(256) hproj_kernel(const float* __restrict__ hh,
                                                    const float* __restrict__ We1) {
  __shared__ float Ast[32][72];  // [k][m]
  __shared__ float Bs[32][72];   // [k][n]
  const int tid = threadIdx.x;
  const int tx = tid & 15, ty = tid >> 4;
  const int n0 = blockIdx.x << 6;
  const int m0 = blockIdx.y << 6;
  float acc[4][4] = {};
  for (int k0 = 0; k0 < H_; k0 += 32) {
    {
      int row = tid >> 2, kq = (tid & 3) << 3;
      const float* src = hh + (size_t)(m0 + row) * H_ + k0 + kq;
      float4 v0 = *(const float4*)src;
      float4 v1 = *(const float4*)(src + 4);
      Ast[kq + 0][row] = v0.x; Ast[kq + 1][row] = v0.y;
      Ast[kq + 2][row] = v0.z; Ast[kq + 3][row] = v0.w;
      Ast[kq + 4][row] = v1.x; Ast[kq + 5][row] = v1.y;
      Ast[kq + 6][row] = v1.z; Ast[kq + 7][row] = v1.w;
    }
    {
      int kr = tid >> 3, nq = (tid & 7) << 3;
      const float* src = We1 + (size_t)(k0 + kr) * H_ + n0 + nq;
      float4 v0 = *(const float4*)src;
      float4 v1 = *(const float4*)(src + 4);
      float* d = &Bs[kr][nq];
      d[0] = v0.x; d[1] = v0.y; d[2] = v0.z; d[3] = v0.w;
      d[4] = v1.x; d[5] = v1.y; d[6] = v1.z; d[7] = v1.w;
    }
    __syncthreads();
#pragma unroll
    for (int kk = 0; kk < 32; ++kk) {
      const float4 a4 = *(const float4*)&Ast[kk][ty << 2];
      const float4 b4 = *(const float4*)&Bs[kk][tx << 2];
      float av[4] = {a4.x, a4.y, a4.z, a4.w};
      float bv[4] = {b4.x, b4.y, b4.z, b4.w};
#pragma unroll
      for (int i = 0; i < 4; ++i)
#pragma unroll
        for (int j = 0; j < 4; ++j) acc[i][j] = fmaf(av[i], bv[j], acc[i][j]);
    }
    __syncthreads();
  }
#pragma unroll
  for (int i = 0; i < 4; ++i) {
    u16* dst = g_hp + (size_t)(m0 + ty * 4 + i) * H_ + n0 + tx * 4;
    u32 w0 = (u32)f2bf(acc[i][0]) | ((u32)f2bf(acc[i][1]) << 16);
    u32 w1 = (u32)f2bf(acc[i][2]) | ((u32)f2bf(acc[i][3]) << 16);
    *(u32*)dst = w0;
    *(u32*)(dst + 2) = w1;
  }
}

// unpack 8 bf16 (uint4) + fma against broadcast scalar
#define FMA8(pk, sk, A)                                          \
  {                                                              \
    u32 ww0 = pk.x, ww1 = pk.y, ww2 = pk.z, ww3 = pk.w;          \
    A[0] = fmaf(sk, bf2f((u16)(ww0 & 0xffffu)), A[0]);           \
    A[1] = fmaf(sk, bf2f((u16)(ww0 >> 16)), A[1]);               \
    A[2] = fmaf(sk, bf2f((u16)(ww1 & 0xffffu)), A[2]);           \
    A[3] = fmaf(sk, bf2f((u16)(ww1 >> 16)), A[3]);               \
    A[4] = fmaf(sk, bf2f((u16)(ww2 & 0xffffu)), A[4]);           \
    A[5] = fmaf(sk, bf2f((u16)(ww2 >> 16)), A[5]);               \
    A[6] = fmaf(sk, bf2f((u16)(ww3 & 0xffffu)), A[6]);           \
    A[7] = fmaf(sk, bf2f((u16)(ww3 >> 16)), A[7]);               \
  }

// ---- step kernel 1 ----
// E-blocks: y-chain (k-split GEMV, 8-col vectors). O-blocks: sp -> e -> softmax -> c.
// LDS: sm[0:512] vecA, sm[512:1024] vecB, sm[1024:1280] e/a (O), partials at PT.
#define PT 1536
__global__ void __launch_bounds__(512) k_step1(float* __restrict__ out, int t) {
  __shared__ __align__(16) float sm[5632];
  __shared__ float red[16];
  __shared__ float w2s[512];
  const int tid = threadIdx.x;
  const int blk = blockIdx.x;
  const int b    = ((blk >> 4) << 3) | (blk & 7);
  const int half = (blk >> 3) & 1;
  const float* scur = (t & 1) ? g_sB : g_sA;

  sm[tid] = scur[b * H_ + tid];
  if (half) w2s[tid] = bf2f(cWe2[tid]);
  __syncthreads();

  if (half == 0) {
    const int c = tid & 63, ks = tid >> 6;
    const int n0 = c << 3, kb = ks << 6;
    // ---- y1 = tanh(s@Wy1+by1): in sm[0:512] -> out sm[512:1024] ----
    {
      float a[8] = {};
      const u16* w = cWy1 + (size_t)kb * H_ + n0;
      for (int k = 0; k < 64; ++k) {
        uint4 pk = *(const uint4*)(w + (size_t)k * H_);
        float sk = sm[kb + k];
        FMA8(pk, sk, a);
      }
      float* pt = &sm[PT + ks * 512 + n0];
#pragma unroll
      for (int j = 0; j < 8; ++j) pt[j] = a[j];
    }
    __syncthreads();
    {
      float v = bf2f(cby1[tid]);
#pragma unroll
      for (int kk = 0; kk < 8; ++kk) v += sm[PT + kk * 512 + tid];
      sm[512 + tid] = ftanh(v);
    }
    __syncthreads();
    // ---- y2: in sm[512:1024] -> out sm[0:512] ----
    {
      float a[8] = {};
      const u16* w = cWy2 + (size_t)kb * H_ + n0;
      for (int k = 0; k < 64; ++k) {
        uint4 pk = *(const uint4*)(w + (size_t)k * H_);
        float sk = sm[512 + kb + k];
        FMA8(pk, sk, a);
      }
      float* pt = &sm[PT + ks * 512 + n0];
#pragma unroll
      for (int j = 0; j < 8; ++j) pt[j] = a[j];
    }
    __syncthreads();
    {
      float v = bf2f(cby2[tid]);
#pragma unroll
      for (int kk = 0; kk < 8; ++kk) v += sm[PT + kk * 512 + tid];
      sm[tid] = ftanh(v);
    }
    __syncthreads();
    // ---- y3 = y2@Wy3+by3 (N=256, 16-way k-split): in sm[0:512] ----
    {
      const int c3 = tid & 31, ks3 = tid >> 5;     // 32 col-groups, 16 k-splits
      const int m0 = c3 << 3, kb3 = ks3 << 5;      // 8 cols, 32 k's
      float a[8] = {};
      const u16* w = cWy3 + (size_t)kb3 * O_ + m0;
      for (int k = 0; k < 32; ++k) {
        uint4 pk = *(const uint4*)(w + (size_t)k * O_);
        float sk = sm[kb3 + k];
        FMA8(pk, sk, a);
      }
      float* pt = &sm[PT + ks3 * 256 + m0];
#pragma unroll
      for (int j = 0; j < 8; ++j) pt[j] = a[j];
    }
    __syncthreads();
    if (tid < O_) {
      float v = bf2f(cby3[tid]);
#pragma unroll
      for (int kk = 0; kk < 16; ++kk) v += sm[PT + kk * 256 + tid];
      g_x[b * X_ + tid] = v;
      out[((size_t)b * T_ + t) * O_ + tid] = v;   // fp32 store
    }
  } else {
    const int c = tid & 63, ks = tid >> 6;
    const int n0 = c << 3, kb = ks << 6;
    // ---- sp = s@We1[H:]+be1: in sm[0:512] -> out sm[512:1024] ----
    {
      float a[8] = {};
      const u16* w = cWe1 + (size_t)(H_ + kb) * H_ + n0;
      for (int k = 0; k < 64; ++k) {
        uint4 pk = *(const uint4*)(w + (size_t)k * H_);
        float sk = sm[kb + k];
        FMA8(pk, sk, a);
      }
      float* pt = &sm[PT + ks * 512 + n0];
#pragma unroll
      for (int j = 0; j < 8; ++j) pt[j] = a[j];
    }
    __syncthreads();
    {
      float v = bf2f(cbe1[tid]);
#pragma unroll
      for (int kk = 0; kk < 8; ++kk) v += sm[PT + kk * 512 + tid];
      sm[512 + tid] = v;
    }
    __syncthreads();
    const int wv = tid >> 6, ln = tid & 63;
    // ---- e[tp] = sum tanh(hp+sp)*We2 ----
    {
      const float* spb = &sm[512 + (ln << 3)];
      const float* w2b = &w2s[ln << 3];
      for (int tp = wv; tp < T_; tp += 8) {
        const u16* hpp = g_hp + ((size_t)(b * T_ + tp) << 9) + (ln << 3);
        uint4 pk = *(const uint4*)hpp;
        u32 ww[4] = {pk.x, pk.y, pk.z, pk.w};
        float part = 0.f;
#pragma unroll
        for (int jj = 0; jj < 4; ++jj) {
          float lo = bf2f((u16)(ww[jj] & 0xffffu));
          float hi = bf2f((u16)(ww[jj] >> 16));
          float a0 = fminf((lo + spb[2 * jj]) * TWOLOG2E_F, 80.f);
          float a1 = fminf((hi + spb[2 * jj + 1]) * TWOLOG2E_F, 80.f);
          float z0 = EXP2(a0), z1 = EXP2(a1);
          float t0 = (z0 - 1.f) * RCPF(z0 + 1.f);
          float t1 = (z1 - 1.f) * RCPF(z1 + 1.f);
          part = fmaf(t0, w2b[2 * jj], part);
          part = fmaf(t1, w2b[2 * jj + 1], part);
        }
#pragma unroll
        for (int off = 32; off > 0; off >>= 1) part += __shfl_down(part, off, 64);
        if (ln == 0) sm[1024 + tp] = part;
      }
    }
    __syncthreads();
    // ---- softmax ----
    float v = (tid < T_) ? sm[1024 + tid] : -3.0e38f;
    float m = v;
#pragma unroll
    for (int off = 32; off > 0; off >>= 1) m = fmaxf(m, __shfl_xor(m, off, 64));
    if (ln == 0) red[wv] = m;
    __syncthreads();
    m = fmaxf(fmaxf(fmaxf(red[0], red[1]), fmaxf(red[2], red[3])),
              fmaxf(fmaxf(red[4], red[5]), fmaxf(red[6], red[7])));
    float pe = (tid < T_) ? EXP2((v - m) * LOG2E_F) : 0.f;
    float ssum = pe;
#pragma unroll
    for (int off = 32; off > 0; off >>= 1) ssum += __shfl_xor(ssum, off, 64);
    if (ln == 0) red[8 + wv] = ssum;
    __syncthreads();
    float tot = (red[8] + red[9]) + (red[10] + red[11]) +
                (red[12] + red[13]) + (red[14] + red[15]);
    float ainv = RCPF(tot);
    if (tid < T_) sm[1024 + tid] = pe * ainv;
    __syncthreads();
    // ---- c = a @ h (8 tp-splits, 8-col vectors) ----
    {
      const int ts = tid >> 6;
      float a[8] = {};
      const u16* hb = g_hb + (size_t)b * T_ * H_ + n0;
      for (int tp = ts * 32; tp < ts * 32 + 32; ++tp) {
        uint4 pk = *(const uint4*)(hb + (size_t)tp * H_);
        float av = sm[1024 + tp];
        FMA8(pk, av, a);
      }
      float* pt = &sm[PT + ts * 512 + n0];
#pragma unroll
      for (int j = 0; j < 8; ++j) pt[j] = a[j];
    }
    __syncthreads();
    {
      float v2 = 0.f;
#pragma unroll
      for (int kk = 0; kk < 8; ++kk) v2 += sm[PT + kk * 512 + tid];
      g_x[b * X_ + O_ + tid] = v2;
    }
  }
}

// ---- step kernel 2: r|u = sigmoid(x@Wx + s@Wh + b)  [audited] ----
__global__ void __launch_bounds__(512) k_step2(int t) {
  __shared__ __align__(16) float sm[7168];
  const int tid = threadIdx.x;
  const int blk = blockIdx.x;
  const int b0 = (blk >> 3) << 2, j8 = blk & 7;
  const float* scur = (t & 1) ? g_sB : g_sA;

  for (int i = tid; i < 5120; i += 512) {
    int k = i >> 2, bl = i & 3;
    sm[i] = (k < X_) ? g_x[(b0 + bl) * X_ + k] : scur[(b0 + bl) * H_ + (k - X_)];
  }
  __syncthreads();
  {
    const int c = tid & 127, ks = tid >> 7;
    const int col = (j8 << 7) + c;
    const bool isU = (col >= H_);
    const int n = isU ? (col - H_) : col;
    const u16* Wx = isU ? cWxu : cWxr;
    const u16* Wh = isU ? cWhu : cWhr;
    float ax = 0.f, ay = 0.f, az = 0.f, aw = 0.f;
    int k0 = ks * 320, k1 = k0 + 320;
    int kxe = (k1 < X_) ? k1 : X_;
#pragma unroll 4
    for (int k = k0; k < kxe; ++k) {
      float w = bf2f(Wx[(size_t)k * H_ + n]);
      const float4 xv = *(const float4*)&sm[k << 2];
      ax = fmaf(xv.x, w, ax); ay = fmaf(xv.y, w, ay);
      az = fmaf(xv.z, w, az); aw = fmaf(xv.w, w, aw);
    }
    int khs = (k0 > X_) ? k0 : X_;
#pragma unroll 4
    for (int k = khs; k < k1; ++k) {
      float w = bf2f(Wh[(size_t)(k - X_) * H_ + n]);
      const float4 xv = *(const float4*)&sm[k << 2];
      ax = fmaf(xv.x, w, ax); ay = fmaf(xv.y, w, ay);
      az = fmaf(xv.z, w, az); aw = fmaf(xv.w, w, aw);
    }
    sm[5120 + (ks * 4 + 0) * 128 + c] = ax;
    sm[5120 + (ks * 4 + 1) * 128 + c] = ay;
    sm[5120 + (ks * 4 + 2) * 128 + c] = az;
    sm[5120 + (ks * 4 + 3) * 128 + c] = aw;
  }
  __syncthreads();
  {
    const int c = tid & 127, bl = tid >> 7;
    const int col = (j8 << 7) + c;
    const bool isU = (col >= H_);
    const int n = isU ? (col - H_) : col;
    float s4 = sm[5120 + (0 * 4 + bl) * 128 + c] + sm[5120 + (1 * 4 + bl) * 128 + c] +
               sm[5120 + (2 * 4 + bl) * 128 + c] + sm[5120 + (3 * 4 + bl) * 128 + c];
    s4 += bf2f((isU ? cbu : cbr)[n]);
    float g = fsigm(s4);
    (isU ? g_u : g_r)[(b0 + bl) * H_ + n] = g;
  }
}

// ---- step kernel 3: h_cand = tanh(x@Wxh + (r*s)@Whh); s update  [audited] ----
__global__ void __launch_bounds__(512) k_step3(int t) {
  __shared__ __align__(16) float sm[7168];
  const int tid = threadIdx.x;
  const int blk = blockIdx.x;
  const int b0 = (blk >> 3) << 2, j8 = blk & 7;
  const float* scur = (t & 1) ? g_sB : g_sA;
  float* snxt       = (t & 1) ? g_sA : g_sB;

  for (int i = tid; i < 5120; i += 512) {
    int k = i >> 2, bl = i & 3;
    float vv;
    if (k < X_) vv = g_x[(b0 + bl) * X_ + k];
    else { int idx = (b0 + bl) * H_ + (k - X_); vv = g_r[idx] * scur[idx]; }
    sm[i] = vv;
  }
  __syncthreads();
  {
    const int c = tid & 63, ks = tid >> 6;
    const int col = (j8 << 6) + c;
    float ax = 0.f, ay = 0.f, az = 0.f, aw = 0.f;
    int k0 = ks * 160, k1 = k0 + 160;
    int kxe = (k1 < X_) ? k1 : X_;
#pragma unroll 4
    for (int k = k0; k < kxe; ++k) {
      float w = bf2f(cWxh[(size_t)k * H_ + col]);
      const float4 xv = *(const float4*)&sm[k << 2];
      ax = fmaf(xv.x, w, ax); ay = fmaf(xv.y, w, ay);
      az = fmaf(xv.z, w, az); aw = fmaf(xv.w, w, aw);
    }
    int khs = (k0 > X_) ? k0 : X_;
#pragma unroll 4
    for (int k = khs; k < k1; ++k) {
      float w = bf2f(cWhh[(size_t)(k - X_) * H_ + col]);
      const float4 xv = *(const float4*)&sm[k << 2];
      ax = fmaf(xv.x, w, ax); ay = fmaf(xv.y, w, ay);
      az = fmaf(xv.z, w, az); aw = fmaf(xv.w, w, aw);
    }
    sm[5120 + (ks * 4 + 0) * 64 + c] = ax;
    sm[5120 + (ks * 4 + 1) * 64 + c] = ay;
    sm[5120 + (ks * 4 + 2) * 64 + c] = az;
    sm[5120 + (ks * 4 + 3) * 64 + c] = aw;
  }
  __syncthreads();
  if (tid < 256) {
    const int c = tid & 63, bl = tid >> 6;
    const int col = (j8 << 6) + c;
    float s8 = 0.f;
#pragma unroll
    for (int kk = 0; kk < 8; ++kk) s8 += sm[5120 + (kk * 4 + bl) * 64 + c];
    float hc = ftanh(s8);
    int idx = (b0 + bl) * H_ + col;
    float uu = g_u[idx];
    snxt[idx] = (1.f - uu) * hc + uu * scur[idx];
  }
}

extern "C" void kernel_launch(void* const* d_in, const int* in_sizes, int n_in,
                              void* d_out, int out_size, void* d_ws, size_t ws_size,
                              hipStream_t stream) {
  (void)in_sizes; (void)n_in; (void)out_size; (void)d_ws; (void)ws_size;
  const float* h  = (const float*)d_in[0];
  const float* s0 = (const float*)d_in[1];
  float* out = (float*)d_out;

#define CONV(NAME, IDX, N) \
  hipLaunchKernelGGL(conv_##NAME, dim3(((N) + 255) / 256), dim3(256), 0, stream, \
                     (const float*)d_in[IDX])
  CONV(Wy1, 2, H_ * H_);
  CONV(by1, 3, H_);
  CONV(Wy2, 4, H_ * H_);
  CONV(by2, 5, H_);
  CONV(Wy3, 6, H_ * O_);
  CONV(by3, 7, O_);
  CONV(We1, 8, 2 * H_ * H_);
  CONV(be1, 9, H_);
  CONV(We2, 10, H_);
  // d_in[11] = be2: softmax shift-invariant, unused
  CONV(Wxr, 12, X_ * H_);
  CONV(Whr, 13, H_ * H_);
  CONV(br, 14, H_);
  CONV(Wxu, 15, X_ * H_);
  CONV(Whu, 16, H_ * H_);
  CONV(bu, 17, H_);
  CONV(Wxh, 18, X_ * H_);
  CONV(Whh, 19, H_ * H_);
#undef CONV
  hipLaunchKernelGGL(conv_h, dim3((B_ * T_ * H_) / 256), dim3(256), 0, stream, h);
  hipLaunchKernelGGL(init_kernel, dim3(256), dim3(256), 0, stream, s0);
  hipLaunchKernelGGL(hproj_kernel, dim3(8, 512), dim3(256), 0, stream, h,
                     (const float*)d_in[8]);

  for (int t = 0; t < T_; ++t) {
    hipLaunchKernelGGL(k_step1, dim3(256), dim3(512), 0, stream, out, t);
    hipLaunchKernelGGL(k_step2, dim3(256), dim3(512), 0, stream, t);
    hipLaunchKernelGGL(k_step3, dim3(256), dim3(512), 0, stream, t);
  }
}